// Round 6
// baseline (66.062 us; speedup 1.0000x reference)
//
#include <hip/hip_runtime.h>
#include <hip/hip_bf16.h>

#define NN 4096
#define FF 128

typedef __attribute__((ext_vector_type(8))) short bf16x8;
typedef __attribute__((ext_vector_type(4))) float f32x4;

// ---------------------------------------------------------------------------
// Detect adjacency encoding. bit1 -> float32 ; else bit0 -> uint8 ; else int32.
__global__ __launch_bounds__(256) void detect_fmt(const unsigned int* __restrict__ w,
                                                  int nwords, int* __restrict__ flag) {
    unsigned int hi = 0u, fl = 0u;
    for (int idx = blockIdx.x * blockDim.x + threadIdx.x; idx < nwords;
         idx += gridDim.x * blockDim.x) {
        unsigned int v = w[idx];
        hi |= (v & 0xFFFFFF00u);
        fl |= (v == 0x3F800000u) ? 1u : 0u;
    }
    int bits = (hi ? 1 : 0) | (fl ? 2 : 0);
    if (bits) atomicOr(flag, bits);
}

// ---------------------------------------------------------------------------
// h = x @ W^T  (f32, used by attn_coef and the bf16 transpose)
__global__ __launch_bounds__(256) void gemm_h(const float* __restrict__ x,
                                              const float* __restrict__ W,
                                              float* __restrict__ h) {
    __shared__ float xs[16][FF];
    int r0 = blockIdx.x * 16;
    const float4* xv = (const float4*)(x + (size_t)r0 * FF);
    float4* xsv = (float4*)&xs[0][0];
    for (int t = threadIdx.x; t < 16 * FF / 4; t += 256) xsv[t] = xv[t];
    __syncthreads();

    int c  = threadIdx.x & 127;
    int rr = threadIdx.x >> 7;
    float acc[8] = {0.f, 0.f, 0.f, 0.f, 0.f, 0.f, 0.f, 0.f};
    for (int k = 0; k < FF; k += 4) {
        float4 w4 = *(const float4*)&W[(size_t)c * FF + k];
#pragma unroll
        for (int r8 = 0; r8 < 8; ++r8) {
            float4 x4 = *(const float4*)&xs[rr + r8 * 2][k];
            acc[r8] += w4.x * x4.x + w4.y * x4.y + w4.z * x4.z + w4.w * x4.w;
        }
    }
#pragma unroll
    for (int r8 = 0; r8 < 8; ++r8)
        h[(size_t)(r0 + rr + r8 * 2) * FF + c] = acc[r8];
}

// ---------------------------------------------------------------------------
// hbfT[f][i] = bf16(h[i][f]) : 64x64 LDS tile transpose, coalesced both sides.
__global__ __launch_bounds__(256) void transpose_bf(const float* __restrict__ h,
                                                    unsigned short* __restrict__ hbfT) {
    __shared__ unsigned short tile[64][66];
    int i0 = (int)(blockIdx.x >> 1) * 64;
    int f0 = (int)(blockIdx.x & 1) * 64;
    int t = threadIdx.x;
#pragma unroll
    for (int k = 0; k < 16; ++k) {
        int idx = k * 256 + t;
        int r = idx >> 6, c = idx & 63;
        float v = h[(size_t)(i0 + r) * FF + f0 + c];
        __hip_bfloat16 b = __float2bfloat16(v);
        union { __hip_bfloat16 b; unsigned short s; } cv; cv.b = b;
        tile[r][c] = cv.s;
    }
    __syncthreads();
#pragma unroll
    for (int k = 0; k < 16; ++k) {
        int idx = k * 256 + t;
        int f = idx >> 6, rr = idx & 63;
        hbfT[(size_t)(f0 + f) * NN + i0 + rr] = tile[rr][f];
    }
}

// ---------------------------------------------------------------------------
// attn coefficients: asrc[i][4] and TRANSPOSED adstT[h][i]. One wave per node.
__global__ __launch_bounds__(256) void attn_coef(const float* __restrict__ h,
                                                 const float* __restrict__ a_src,
                                                 const float* __restrict__ a_dst,
                                                 float* __restrict__ asrc,
                                                 float* __restrict__ adstT) {
    int lane = threadIdx.x & 63;
    int i = blockIdx.x * 4 + (threadIdx.x >> 6);
    float h0 = h[(size_t)i * FF + lane];
    float h1 = h[(size_t)i * FF + 64 + lane];
    int d  = lane & 31;
    int hA = lane >> 5;
    int hB = hA + 2;
    float s0 = h0 * a_src[hA * 32 + d], s1 = h1 * a_src[hB * 32 + d];
    float d0 = h0 * a_dst[hA * 32 + d], d1 = h1 * a_dst[hB * 32 + d];
#pragma unroll
    for (int m = 16; m >= 1; m >>= 1) {
        s0 += __shfl_xor(s0, m); s1 += __shfl_xor(s1, m);
        d0 += __shfl_xor(d0, m); d1 += __shfl_xor(d1, m);
    }
    if (d == 0) {
        asrc[i * 4 + hA] = s0; asrc[i * 4 + hB] = s1;
        adstT[(size_t)hA * NN + i] = d0; adstT[(size_t)hB * NN + i] = d1;
    }
}

// ---------------------------------------------------------------------------
// Dense flash-style GAT aggregation with MFMA. Grid = 64 i-tiles x 8 j-chunks.
// Block: 512 threads = 8 waves; i-tile = 64 rows; j-chunk = 512 cols, swept in
// 16 steps of 32. Wave w -> (head = w>>1, isub-pair = w&1): builds P fragments
// (rank-1 score + LeakyReLU + exp + adj mask, bf16) for 2 i-subtiles, and runs
// 4 mfma_f32_16x16x32_bf16 per step (2 isubs x 2 f-halves of its head).
// Staging (T14 split): SL issues global loads to regs early; SW writes LDS
// after compute; one barrier per step. hT LDS pitch 40 u16 (16B-aligned rows,
// ~2-way bank conflict on b128 reads = near-free). Partial numerators (f32)
// and denominators per j-chunk go to workspace; gat_combine reduces.
__global__ __launch_bounds__(512, 4) void gat_dense(const unsigned short* __restrict__ hbfT,
                                                    const float* __restrict__ asrc,
                                                    const float* __restrict__ adstT,
                                                    const void* __restrict__ adj,
                                                    const int* __restrict__ flag,
                                                    float* __restrict__ num_ws,
                                                    float* __restrict__ den_ws) {
    __shared__ unsigned short sT[2][128 * 40];
    __shared__ unsigned char  sAdj[2][64 * 40];

    const int t    = threadIdx.x;
    const int lane = t & 63;
    const int wv   = t >> 6;
    const int head = wv >> 1;
    const int half = wv & 1;
    const int i0   = (int)(blockIdx.x >> 3) * 64;
    const int jc   = (int)blockIdx.x & 7;
    const int jb   = jc * 512;
    const int fmt  = *flag;

    // staging thread roles
    const int sf = t >> 2, sp = t & 3;     // hT: feature row, 8-j part
    const int ar = t >> 3, ac = t & 7;     // adj: row, 4-byte group
    const unsigned short* gT  = hbfT + (size_t)sf * NN + jb + sp * 8;
    const unsigned char*  gA8 = (const unsigned char*)adj + (size_t)(i0 + ar) * NN + jb + ac * 4;
    const int*   gA32 = (const int*)adj   + (size_t)(i0 + ar) * NN + jb + ac * 4;
    const float* gAf  = (const float*)adj + (size_t)(i0 + ar) * NN + jb + ac * 4;

    // compute-lane constants
    const int row = lane & 15;             // A row / B col
    const int kg  = lane >> 4;             // k-group: k = kg*8 + e
    const int isubA = half * 2, isubB = half * 2 + 1;
    const float svA = asrc[(size_t)(i0 + isubA * 16 + row) * 4 + head];
    const float svB = asrc[(size_t)(i0 + isubB * 16 + row) * 4 + head];
    const float* gD = adstT + (size_t)head * NN + jb + kg * 8;

    f32x4 accA0 = {0.f,0.f,0.f,0.f}, accA1 = {0.f,0.f,0.f,0.f};
    f32x4 accB0 = {0.f,0.f,0.f,0.f}, accB1 = {0.f,0.f,0.f,0.f};
    float denA = 0.f, denB = 0.f;

    uint4 rT; unsigned int rA1;
    float4 rD0n, rD1n, rD0c, rD1c;

#define SL(step) do {                                                          \
        rT = *(const uint4*)(gT + (size_t)(step) * 32);                        \
        rD0n = *(const float4*)(gD + (step) * 32);                             \
        rD1n = *(const float4*)(gD + (step) * 32 + 4);                         \
        if (fmt == 1) { rA1 = *(const unsigned int*)(gA8 + (step) * 32); }     \
        else if (fmt & 2) { float4 fv = *(const float4*)(gAf + (step) * 32);   \
            rA1 = (fv.x!=0.f?1u:0u) | (fv.y!=0.f?0x100u:0u) |                  \
                  (fv.z!=0.f?0x10000u:0u) | (fv.w!=0.f?0x1000000u:0u); }       \
        else { int4 iv = *(const int4*)(gA32 + (step) * 32);                   \
            rA1 = (iv.x?1u:0u) | (iv.y?0x100u:0u) |                            \
                  (iv.z?0x10000u:0u) | (iv.w?0x1000000u:0u); }                 \
    } while (0)

#define SW(buf) do {                                                           \
        *(uint4*)&sT[(buf)][sf * 40 + sp * 8] = rT;                            \
        *(unsigned int*)&sAdj[(buf)][ar * 40 + ac * 4] = rA1;                  \
    } while (0)

#define ONE_SUB(sv, den, acc0, acc1, isub, Tb, Ab, B0, B1) do {                \
        unsigned long long ad =                                                \
            *(const unsigned long long*)&(Ab)[((isub) * 16 + row) * 40 + kg * 8]; \
        bf16x8 Afr;                                                            \
        _Pragma("unroll")                                                      \
        for (int e = 0; e < 8; ++e) {                                          \
            float xvíz = (sv) + dv[e];                                         \
            float xx = fmaxf(xvíz, 0.2f * xvíz);                               \
            float p = __expf(xx);                                              \
            p = ((ad >> (8 * e)) & 0xFFull) ? p : 0.f;                         \
            (den) += p;                                                        \
            union { __hip_bfloat16 b; short s; } cv;                           \
            cv.b = __float2bfloat16(p);                                        \
            Afr[e] = cv.s;                                                     \
        }                                                                      \
        (acc0) = __builtin_amdgcn_mfma_f32_16x16x32_bf16(Afr, (B0), (acc0), 0, 0, 0); \
        (acc1) = __builtin_amdgcn_mfma_f32_16x16x32_bf16(Afr, (B1), (acc1), 0, 0, 0); \
    } while (0)

#define COMPUTE(buf) do {                                                      \
        const unsigned short* Tb = sT[(buf)];                                  \
        const unsigned char*  Ab = sAdj[(buf)];                                \
        bf16x8 B0 = *(const bf16x8*)&Tb[(head * 32 + row) * 40 + kg * 8];      \
        bf16x8 B1 = *(const bf16x8*)&Tb[(head * 32 + 16 + row) * 40 + kg * 8]; \
        float dv[8] = {rD0c.x, rD0c.y, rD0c.z, rD0c.w,                         \
                       rD1c.x, rD1c.y, rD1c.z, rD1c.w};                        \
        ONE_SUB(svA, denA, accA0, accA1, isubA, Tb, Ab, B0, B1);               \
        ONE_SUB(svB, denB, accB0, accB1, isubB, Tb, Ab, B0, B1);               \
    } while (0)

    SL(0); SW(0); rD0c = rD0n; rD1c = rD1n;
    __syncthreads();
    for (int s = 0; s < 16; ++s) {
        if (s < 15) SL(s + 1);            // issue next-step global loads early
        COMPUTE(s & 1);                   // LDS + VALU + MFMA hides the latency
        if (s < 15) { SW((s + 1) & 1); rD0c = rD0n; rD1c = rD1n; }
        __syncthreads();
    }

    // denominators: lane holds partial over its k-slice; reduce k-groups.
    denA += __shfl_xor(denA, 16); denA += __shfl_xor(denA, 32);
    denB += __shfl_xor(denB, 16); denB += __shfl_xor(denB, 32);
    if (lane < 16) {
        den_ws[((size_t)jc * 4 + head) * NN + i0 + isubA * 16 + lane] = denA;
        den_ws[((size_t)jc * 4 + head) * NN + i0 + isubB * 16 + lane] = denB;
    }

    // C-tiles: col = lane&15, row = (lane>>4)*4 + reg   [verified gfx950 C/D map]
    const int colA = head * 32 + row;
    const int colB = head * 32 + 16 + row;
    const int rbA = i0 + isubA * 16 + kg * 4;
    const int rbB = i0 + isubB * 16 + kg * 4;
#pragma unroll
    for (int r = 0; r < 4; ++r) {
        num_ws[((size_t)jc * NN + rbA + r) * FF + colA] = accA0[r];
        num_ws[((size_t)jc * NN + rbA + r) * FF + colB] = accA1[r];
        num_ws[((size_t)jc * NN + rbB + r) * FF + colA] = accB0[r];
        num_ws[((size_t)jc * NN + rbB + r) * FF + colB] = accB1[r];
    }
#undef SL
#undef SW
#undef ONE_SUB
#undef COMPUTE
}

// ---------------------------------------------------------------------------
// Reduce the 8 j-chunk partials: out = sum(num) / sum(den).
__global__ __launch_bounds__(256) void gat_combine(const float* __restrict__ num_ws,
                                                   const float* __restrict__ den_ws,
                                                   float* __restrict__ out) {
    int id = blockIdx.x * 256 + threadIdx.x;
    int f = id & 127, i = id >> 7;
    int h = f >> 5;
    float num = 0.f, den = 0.f;
#pragma unroll
    for (int jc = 0; jc < 8; ++jc) {
        num += num_ws[((size_t)jc * NN + i) * FF + f];
        den += den_ws[((size_t)jc * 4 + h) * NN + i];
    }
    out[(size_t)i * FF + f] = (den > 0.f) ? num / den : 0.f;
}

// ---------------------------------------------------------------------------
extern "C" void kernel_launch(void* const* d_in, const int* in_sizes, int n_in,
                              void* d_out, int out_size, void* d_ws, size_t ws_size,
                              hipStream_t stream) {
    const float* x     = (const float*)d_in[0];
    const void*  adj   = d_in[1];
    const float* W     = (const float*)d_in[2];
    const float* a_src = (const float*)d_in[3];
    const float* a_dst = (const float*)d_in[4];
    float* out = (float*)d_out;

    char* ws = (char*)d_ws;
    float*          h     = (float*)ws;                       // 2 MiB @ 0
    unsigned short* hbfT  = (unsigned short*)(ws + (2u<<20)); // 1 MiB @ 2M
    float*          asrc  = (float*)(ws + (3u<<20));          // 64 KiB @ 3M
    float*          adstT = (float*)(ws + (3u<<20) + 65536);  // 64 KiB
    int*            flag  = (int*)  (ws + (3u<<20) + 131072); // 4 B (+pad)
    float*          numw  = (float*)(ws + (4u<<20));          // 16 MiB @ 4M
    float*          denw  = (float*)(ws + (20u<<20));         // 512 KiB @ 20M

    hipMemsetAsync(flag, 0, sizeof(int), stream);
    detect_fmt  <<<64, 256, 0, stream>>>((const unsigned int*)adj, 65536, flag);
    gemm_h      <<<NN / 16, 256, 0, stream>>>(x, W, h);
    transpose_bf<<<128, 256, 0, stream>>>(h, hbfT);
    attn_coef   <<<NN / 4, 256, 0, stream>>>(h, a_src, a_dst, asrc, adstT);
    gat_dense   <<<512, 512, 0, stream>>>(hbfT, asrc, adstT, adj, flag, numw, denw);
    gat_combine <<<2048, 256, 0, stream>>>(numw, denw, out);
}